// Round 3
// baseline (233.347 us; speedup 1.0000x reference)
//
#include <hip/hip_runtime.h>

#define T_DIM 512
#define B_DIM 8192
#define GB 8                 // batch columns per block
#define NC 128               // time chunks per block
#define LC 4                 // timesteps per chunk (NC*LC == T_DIM)
#define BLOCK (GB * NC)      // 1024 threads
#define GRID (B_DIM / GB)    // 1024 blocks
#define GAMMA 0.99f

// V-trace + PPO loss, single fused kernel, one full read of inputs.
// Identities (valid because RHO_THRESHOLD == C_THRESHOLD == 1):
//   p_t = rho*(r_t - v_t), m_t = gamma*rho*(1-d_t), s_t = v_t + p_t
//   adv_t    = p_t + m_t*carry = (s_t + m_t*carry) - v_t
//   vtrace_t = s_t + m_t*carry  (next_v cancels except the t=T-1 init)
//   v_t - vtrace_t = -adv_t  =>  critic = 0.5*mean(adv^2)
// Per-t replay state lives in LDS (NOT per-thread arrays: rounds 1-2 showed
// the compiler demotes indexed per-thread arrays to scratch -> 48 MB HBM
// write traffic). 48 KB state + 8 KB scan = 56.2 KB/block -> 2 blocks/CU,
// 32 waves/CU, and only ~loop-working-set VGPRs.
__launch_bounds__(BLOCK, 8)
__global__ void vtrace_main(const float* __restrict__ prob,
                            const float* __restrict__ aprob,
                            const float* __restrict__ v,
                            const float* __restrict__ nv,
                            const float* __restrict__ rw,
                            const int* __restrict__ act,
                            const int* __restrict__ dnn,
                            float* __restrict__ ws,
                            float* __restrict__ out) {
    __shared__ float2 RS[LC][BLOCK];   // (rs = done? -ratio : ratio, s)
    __shared__ float  VV[LC][BLOCK];   // v
    __shared__ float  Sc[NC][GB];      // chunk composite S; becomes Cin in scan
    __shared__ float  Mc[NC][GB];      // chunk composite M
    __shared__ float  red[32];

    const int tid = threadIdx.x;
    const int bl  = tid & (GB - 1);
    const int c   = tid >> 3;          // chunk 0..NC-1
    const int b   = blockIdx.x * GB + bl;
    const int t0  = c * LC;

    const float2* __restrict__ prob2  = (const float2*)prob;
    const float2* __restrict__ aprob2 = (const float2*)aprob;

    // ---- phase A: read inputs once, build per-t state in LDS + chunk composite
    float S = 0.0f, M = 1.0f;
#pragma unroll
    for (int i = LC - 1; i >= 0; --i) {
        const int idx = (t0 + i) * B_DIM + b;      // < 2^23, fits int
        float2 pr = prob2[idx];
        float2 qr = aprob2[idx];
        float vv  = v[idx];
        float rr  = rw[idx];
        int   a   = act[idx];
        int   d   = dnn[idx];

        float pa    = a ? pr.y : pr.x;
        float qa    = a ? qr.y : qr.x;
        // ratio = exp(logp - logp_act) == (pa/sum_p) / (qa/sum_q)
        float ratio = (pa * (qr.x + qr.y)) / ((pr.x + pr.y) * qa);
        float rho   = fminf(ratio, 1.0f);
        float m     = d ? 0.0f : GAMMA * rho;
        float s     = fmaf(rho, rr - vv, vv);      // v + rho*(r - v)

        RS[i][tid] = make_float2(d ? -ratio : ratio, s);
        VV[i][tid] = vv;
        // compose F_t(x) = s + m*x in front of running composite
        S = fmaf(m, S, s);
        M = m * M;
    }
    Sc[c][bl] = S;
    Mc[c][bl] = M;
    __syncthreads();

    // ---- serial cross-chunk suffix scan (reverse over time), one thread per b.
    // Overwrites Sc[cc] with the carry ENTERING chunk cc (Cin).
    if (tid < GB) {
        float carry = nv[(T_DIM - 1) * B_DIM + blockIdx.x * GB + tid];
#pragma unroll 8
        for (int cc = NC - 1; cc >= 0; --cc) {
            float s = Sc[cc][tid];
            float m = Mc[cc][tid];
            Sc[cc][tid] = carry;                   // Cin
            carry = fmaf(m, carry, s);
        }
    }
    __syncthreads();

    // ---- phase B: replay chunk from LDS with corrected carry
    float carry  = Sc[c][bl];
    float critic = 0.0f, msum = 0.0f;
#pragma unroll
    for (int i = LC - 1; i >= 0; --i) {
        float2 rs_s = RS[i][tid];
        float  vv   = VV[i][tid];
        float  r_   = fabsf(rs_s.x);
        float  m    = (rs_s.x > 0.0f) ? GAMMA * fminf(r_, 1.0f) : 0.0f;
        float  u    = fmaf(m, carry, rs_s.y);      // vtrace_t
        float  adv  = u - vv;
        carry       = u;
        critic = fmaf(adv, adv, critic);
        float rc = fminf(fmaxf(r_, 0.8f), 1.2f);   // clip(ratio, 1 +/- 0.2)
        msum += fminf(r_ * adv, rc * adv);
    }

    // ---- block reduction: wave64 shuffle, then cross-wave via LDS
#pragma unroll
    for (int off = 32; off > 0; off >>= 1) {
        critic += __shfl_down(critic, off, 64);
        msum   += __shfl_down(msum, off, 64);
    }
    const int wave = tid >> 6;                     // 0..15
    if ((tid & 63) == 0) { red[wave] = critic; red[16 + wave] = msum; }
    __syncthreads();

    if (tid == 0) {
        float cs = 0.0f, ms = 0.0f;
#pragma unroll
        for (int w = 0; w < 16; ++w) { cs += red[w]; ms += red[16 + w]; }
        // device-scope accumulation + ticket; ws zeroed by hipMemsetAsync.
        atomicAdd(&ws[0], cs);
        atomicAdd(&ws[1], ms);
        __threadfence();
        unsigned* cnt = (unsigned*)(ws + 2);
        unsigned ticket = atomicAdd(cnt, 1u);
        if (ticket == GRID - 1) {
            __threadfence();
            float c_tot = atomicAdd(&ws[0], 0.0f); // atomic read-back
            float m_tot = atomicAdd(&ws[1], 0.0f);
            const float invN = 1.0f / (float)((size_t)T_DIM * B_DIM);
            out[0] = 0.5f * c_tot * invN - m_tot * invN;
        }
    }
}

extern "C" void kernel_launch(void* const* d_in, const int* in_sizes, int n_in,
                              void* d_out, int out_size, void* d_ws, size_t ws_size,
                              hipStream_t stream) {
    const float* prob  = (const float*)d_in[0];
    const float* aprob = (const float*)d_in[1];
    const float* v     = (const float*)d_in[2];
    const float* nv    = (const float*)d_in[3];
    const float* rw    = (const float*)d_in[4];
    const int*   act   = (const int*)d_in[5];
    const int*   dnn   = (const int*)d_in[6];
    float* ws  = (float*)d_ws;
    float* out = (float*)d_out;

    hipMemsetAsync(ws, 0, 12, stream);  // ws[0], ws[1], ticket counter
    vtrace_main<<<GRID, BLOCK, 0, stream>>>(prob, aprob, v, nv, rw, act, dnn,
                                            ws, out);
}

// Round 4
// 189.431 us; speedup vs baseline: 1.2318x; 1.2318x over previous
//
#include <hip/hip_runtime.h>

#define T_DIM 512
#define B_DIM 8192
#define NCH   16                 // time chunks
#define LT    32                 // timesteps per chunk (NCH*LT == T_DIM)
#define CG    64                 // columns per wave (one per lane)
#define NCG   (B_DIM / CG)       // 128 column groups
#define WPB   8                  // waves per block
#define K_BLOCK (WPB * 64)       // 512 threads
#define K_GRID  ((NCH * NCG) / WPB)  // 256 blocks
#define GAMMA 0.99f

// Workspace layout (1.5 MB + 12 B):
//   SM  : float2[NCH][B_DIM]  chunk affine composites      @ 0
//   CIN : float [NCH][B_DIM]  carry entering each chunk    @ 1 MB
//   ACC : float[2] + uint ticket                           @ 1.5 MB
#define SM_OFF  0
#define CIN_OFF (NCH * B_DIM * sizeof(float2))
#define ACC_OFF (CIN_OFF + NCH * B_DIM * sizeof(float))

// Identities (RHO_THRESHOLD == C_THRESHOLD == 1):
//   ratio = (p_a * sum_q) / (sum_p * q_a)         [no log/exp]
//   m = gamma*rho*(1-done), s = v + rho*(r - v)
//   vtrace_t = s_t + m_t*carry ; adv_t = vtrace_t - v_t ; critic = 0.5*mean(adv^2)
//   next_v cancels except the t=T-1 scan init.
// Rounds 1-3 showed per-t state in registers -> scratch spills, in LDS ->
// 1 block/CU + serial-scan stall. So: store NOTHING per-t; recompute in the
// replay kernel (second read hits L2/L3 - measured L3-warm replays ran at
// identical speed, we are latency-bound, not HBM-bound).

__device__ __forceinline__ void eval_t(const float2 pr, const float2 qr,
                                       const float vv, const float rr,
                                       const int a, const int d,
                                       float& ratio, float& m, float& s) {
    float pa = a ? pr.y : pr.x;
    float qa = a ? qr.y : qr.x;
    ratio = (pa * (qr.x + qr.y)) / ((pr.x + pr.y) * qa);
    float rho = fminf(ratio, 1.0f);
    m = d ? 0.0f : GAMMA * rho;
    s = fmaf(rho, rr - vv, vv);
}

__launch_bounds__(K_BLOCK, 4)
__global__ void k_comp(const float* __restrict__ prob,
                       const float* __restrict__ aprob,
                       const float* __restrict__ v,
                       const float* __restrict__ rw,
                       const int* __restrict__ act,
                       const int* __restrict__ dnn,
                       float2* __restrict__ SM) {
    const int lane = threadIdx.x & 63;
    const int gw   = blockIdx.x * WPB + (threadIdx.x >> 6);
    const int cg   = gw & (NCG - 1);
    const int ch   = gw >> 7;               // NCG == 128
    const int col  = cg * CG + lane;
    const int t0   = ch * LT;

    const float2* __restrict__ prob2  = (const float2*)prob;
    const float2* __restrict__ aprob2 = (const float2*)aprob;

    float S = 0.0f, M = 1.0f;
#pragma unroll 4
    for (int i = LT - 1; i >= 0; --i) {
        const int idx = (t0 + i) * B_DIM + col;
        float ratio, m, s;
        eval_t(prob2[idx], aprob2[idx], v[idx], rw[idx], act[idx], dnn[idx],
               ratio, m, s);
        S = fmaf(m, S, s);                  // compose F_t in front
        M *= m;
    }
    SM[ch * B_DIM + col] = make_float2(S, M);
}

__global__ void k_scan(const float2* __restrict__ SM,
                       const float* __restrict__ nv,
                       float* __restrict__ CIN) {
    const int col = blockIdx.x * blockDim.x + threadIdx.x;   // 8192 threads
    float carry = nv[(T_DIM - 1) * B_DIM + col];
#pragma unroll
    for (int ch = NCH - 1; ch >= 0; --ch) {
        float2 sm = SM[ch * B_DIM + col];   // independent loads, short fma chain
        CIN[ch * B_DIM + col] = carry;
        carry = fmaf(sm.y, carry, sm.x);
    }
}

__launch_bounds__(K_BLOCK, 4)
__global__ void k_replay(const float* __restrict__ prob,
                         const float* __restrict__ aprob,
                         const float* __restrict__ v,
                         const float* __restrict__ rw,
                         const int* __restrict__ act,
                         const int* __restrict__ dnn,
                         const float* __restrict__ CIN,
                         float* __restrict__ ACC,
                         float* __restrict__ out) {
    __shared__ float red[2 * WPB];
    const int lane = threadIdx.x & 63;
    const int wv   = threadIdx.x >> 6;
    const int gw   = blockIdx.x * WPB + wv;
    const int cg   = gw & (NCG - 1);
    const int ch   = gw >> 7;
    const int col  = cg * CG + lane;
    const int t0   = ch * LT;

    const float2* __restrict__ prob2  = (const float2*)prob;
    const float2* __restrict__ aprob2 = (const float2*)aprob;

    float carry  = CIN[ch * B_DIM + col];
    float critic = 0.0f, msum = 0.0f;
#pragma unroll 4
    for (int i = LT - 1; i >= 0; --i) {
        const int idx = (t0 + i) * B_DIM + col;
        float ratio, m, s;
        eval_t(prob2[idx], aprob2[idx], v[idx], rw[idx], act[idx], dnn[idx],
               ratio, m, s);
        float u   = fmaf(m, carry, s);       // vtrace_t
        float adv = u - v[idx];
        carry     = u;
        critic = fmaf(adv, adv, critic);
        float rc = fminf(fmaxf(ratio, 0.8f), 1.2f);
        msum += fminf(ratio * adv, rc * adv);
    }

    // wave reduce, then cross-wave via LDS
#pragma unroll
    for (int off = 32; off > 0; off >>= 1) {
        critic += __shfl_down(critic, off, 64);
        msum   += __shfl_down(msum, off, 64);
    }
    if (lane == 0) { red[wv] = critic; red[WPB + wv] = msum; }
    __syncthreads();
    if (threadIdx.x == 0) {
        float cs = 0.0f, ms = 0.0f;
#pragma unroll
        for (int w = 0; w < WPB; ++w) { cs += red[w]; ms += red[WPB + w]; }
        atomicAdd(&ACC[0], cs);
        atomicAdd(&ACC[1], ms);
        __threadfence();
        unsigned* cnt = (unsigned*)(ACC + 2);
        if (atomicAdd(cnt, 1u) == K_GRID - 1) {
            __threadfence();
            float c_tot = atomicAdd(&ACC[0], 0.0f);
            float m_tot = atomicAdd(&ACC[1], 0.0f);
            const float invN = 1.0f / (float)((size_t)T_DIM * B_DIM);
            out[0] = 0.5f * c_tot * invN - m_tot * invN;
        }
    }
}

extern "C" void kernel_launch(void* const* d_in, const int* in_sizes, int n_in,
                              void* d_out, int out_size, void* d_ws, size_t ws_size,
                              hipStream_t stream) {
    const float* prob  = (const float*)d_in[0];
    const float* aprob = (const float*)d_in[1];
    const float* v     = (const float*)d_in[2];
    const float* nv    = (const float*)d_in[3];
    const float* rw    = (const float*)d_in[4];
    const int*   act   = (const int*)d_in[5];
    const int*   dnn   = (const int*)d_in[6];

    float2* SM  = (float2*)((char*)d_ws + SM_OFF);
    float*  CIN = (float*)((char*)d_ws + CIN_OFF);
    float*  ACC = (float*)((char*)d_ws + ACC_OFF);
    float*  out = (float*)d_out;

    hipMemsetAsync(ACC, 0, 12, stream);
    k_comp<<<K_GRID, K_BLOCK, 0, stream>>>(prob, aprob, v, rw, act, dnn, SM);
    k_scan<<<B_DIM / 256, 256, 0, stream>>>(SM, nv, CIN);
    k_replay<<<K_GRID, K_BLOCK, 0, stream>>>(prob, aprob, v, rw, act, dnn,
                                             CIN, ACC, out);
}